// Round 15
// baseline (97.672 us; speedup 1.0000x reference)
//
#include <hip/hip_runtime.h>
#include <hip/hip_fp16.h>

// RoI Align, ALIGNED=False, SCALE=160.
// feat: (8, 256, 160, 160) fp32; rois: (1024,5); out: (1024, 256, 14, 14) fp32
//
// R15 = R14 evolved: EIGHT channels per LDS pixel (uint4 = 4x half2, 16 B/px)
// via QUARTER-plane split (41 rows x 164 px x 16 B ~= 107.6 KB). One 16 B
// descriptor + 4 ds_read_b128 + one weight-decode serve 8 channels; inner
// iterations halve vs R14 (6.4M total). Quarter q = y0c/40 computed
// bit-identically in setup & precompute (shared iy_of); q monotone in oy ->
// per-(k,q) chunks contiguous in s-order -> coalesced stores. NT staging
// loads retained (R12/R13 isolation: ~22 µs). Stride-164 bank pad retained.
//
//  1) setup_kernel (1 block): per-ROI quarter row-counts/starts, per-(b,q)
//     stream sizes + per-k chunk offsets (order-independent atomics; each
//     descriptor carries its own outidx -> output deterministic).
//  2) precompute_kernel: uint4 descriptor {bx_local|dyr|wq13|vy0|vy1,
//     ax(half2), outidx, 0} at its in-order chunk slot.
//  3) main: block=(octet o, b, q): zero pads; NT-stage 41 rows of 8 planes
//     as uint4 pixels; gather stream; 8 stores/sample.

#define FM_N 8
#define FM_C 256
#define FM_H 160
#define FM_W 160
#define PLANE (FM_H * FM_W)     // 25600
#define PLANE4 (PLANE / 4)      // 6400
#define OH 14
#define OW 14
#define OSP (OH * OW)           // 196
#define KMAX 1024
#define SCALE_HW 160.0f
#define MAIN_BLK 1024
#define QROWS 40                // quarter height in y0c terms
#define ROWS 41                 // staged rows (1 overlap)
#define LDSW 164                // padded row stride in PIXELS (164*16B: bank-rotating)
#define ROW_F4 (FM_W / 4)       // 40 f4 chunks per source row
#define PL_PIX (ROWS * LDSW)    // 6724 pixels
#define FRONTPAD 1              // 1 pixel (16 B)
#define TAILPAD 4

typedef float f4 __attribute__((ext_vector_type(4)));

// ws layout (int32 units):
//   [0..32)    cnt32[b*4+q]  (stream sizes, samples)
//   [32..64)   soff32        (exclusive prefix, samples)
//   [64..64+8*KMAX) kinfo[k] = {off[4], start_oy[4]}
//   byte 33024: samples[K*196] as uint4
#define WS_KINFO_OFF 64
#define WS_SAMPLES_BYTE_OFF 33024

// Shared between setup & precompute so the quarter test is bit-identical.
__device__ __forceinline__ float iy_of(float y1, float y2, int oy) {
  return fmaf((float)oy * (1.0f / (OH - 1)), y2 - y1, y1) - 0.5f;
}

__device__ __forceinline__ int quarter_of(float y1, float y2, int oy) {
  const int y0 = (int)floorf(iy_of(y1, y2, oy));
  const int y0c = min(max(y0, 0), FM_H - 1);
  return y0c / QROWS;  // 0..3
}

__global__ __launch_bounds__(1024) void setup_kernel(
    const float* __restrict__ rois, int K, int* __restrict__ ws) {
  __shared__ int cnt[32];
  __shared__ int soff[32];
  const int t = threadIdx.x;
  if (t < 32) cnt[t] = 0;
  __syncthreads();
  int n[4] = {0, 0, 0, 0};
  int st[4] = {0, 0, 0, 0};
  int pos[4] = {0, 0, 0, 0};
  int b = 0;
  if (t < K) {
    b = (int)rois[t * 5];
    const float y1 = rois[t * 5 + 2] * SCALE_HW;
    const float y2 = rois[t * 5 + 4] * SCALE_HW;
#pragma unroll
    for (int oy = 0; oy < OH; ++oy) {
      const int q = quarter_of(y1, y2, oy);   // monotone non-decreasing
      if (n[q] == 0) st[q] = oy;
      n[q]++;
    }
#pragma unroll
    for (int q = 0; q < 4; ++q)
      if (n[q]) pos[q] = atomicAdd(&cnt[b * 4 + q], n[q] * OW);
  }
  __syncthreads();
  if (t == 0) {
    int acc = 0;
    for (int i = 0; i < 32; ++i) { soff[i] = acc; acc += cnt[i]; }
  }
  __syncthreads();
  if (t < 32) { ws[t] = cnt[t]; ws[32 + t] = soff[t]; }
  if (t < K) {
#pragma unroll
    for (int q = 0; q < 4; ++q) {
      ws[WS_KINFO_OFF + 8 * t + q] = soff[b * 4 + q] + pos[q];
      ws[WS_KINFO_OFF + 8 * t + 4 + q] = st[q];
    }
  }
}

__global__ __launch_bounds__(256) void precompute_kernel(
    const float* __restrict__ rois, const int* __restrict__ ws, int total,
    uint4* __restrict__ samples) {
  const int g = blockIdx.x * 256 + threadIdx.x;
  if (g >= total) return;
  const int k = g / OSP;
  const int s = g - k * OSP;
  const int oy = s / OW;
  const int ox = s - oy * OW;

  const float x1 = rois[k * 5 + 1] * SCALE_HW;
  const float y1 = rois[k * 5 + 2] * SCALE_HW;
  const float x2 = rois[k * 5 + 3] * SCALE_HW;
  const float y2 = rois[k * 5 + 4] * SCALE_HW;

  // ALIGNED=False index math collapses to ix = fx - 0.5
  const float ix = fmaf((float)ox * (1.0f / (OW - 1)), x2 - x1, x1) - 0.5f;
  const float iy = iy_of(y1, y2, oy);

  const float fx0 = floorf(ix);
  const float fy0 = floorf(iy);
  const int x0 = (int)fx0;
  const int y0 = (int)fy0;
  const float wx1 = ix - fx0;
  const float wy1 = iy - fy0;

  const bool vx0 = (x0 >= 0 && x0 < FM_W);
  const bool vx1 = (x0 + 1 >= 0 && x0 + 1 < FM_W);
  const unsigned vy0 = (y0 >= 0 && y0 < FM_H) ? 1u : 0u;
  const unsigned vy1 = (y0 + 1 >= 0 && y0 + 1 < FM_H) ? 1u : 0u;

  const int x0c = min(max(x0, 0), FM_W - 1);
  const int x1c = min(max(x0 + 1, 0), FM_W - 1);
  const int y0c = min(max(y0, 0), FM_H - 1);
  const int y1c = min(max(y0 + 1, 0), FM_H - 1);

  const int q = y0c / QROWS;        // bit-identical to setup's quarter_of
  const int row0 = q * QROWS;

  // Quarter-local, stride-164 pixel coordinates.
  const int yl0 = y0c - row0;       // 0..39
  const int o00 = yl0 * LDSW + x0c;
  const int o01 = yl0 * LDSW + x1c;
  // Left-base: corners always {pix[bx], pix[bx+1]}; border cases carry zero
  // ax weight on the garbage side (pads zeroed in main kernel).
  const int bx = vx1 ? (o01 - 1) : o00;            // [-1, 6554]
  const unsigned bxs = (unsigned)(bx + FRONTPAD);  // 13 bits
  const unsigned dyr = (unsigned)(y1c - y0c);      // 0/1
  unsigned wq = (unsigned)(wy1 * 8192.0f + 0.5f);
  wq = wq > 8191u ? 8191u : wq;

  const __half2 axh = __floats2half2_rn((1.0f - wx1) * (vx0 ? 1.0f : 0.0f),
                                        wx1 * (vx1 ? 1.0f : 0.0f));
  uint4 sd;
  sd.x = bxs | (dyr << 15) | (wq << 16) | (vy0 << 29) | (vy1 << 30);
  sd.y = *(const unsigned*)&axh;
  sd.z = (unsigned)(k * (FM_C * OSP) + s);  // out index (+ c*OSP at store)
  sd.w = 0;

  const int coff = ws[WS_KINFO_OFF + 8 * k + q];
  const int stq = ws[WS_KINFO_OFF + 8 * k + 4 + q];
  samples[coff + (oy - stq) * OW + ox] = sd;
}

__global__ __launch_bounds__(MAIN_BLK) void roi_align_main_kernel(
    const float* __restrict__ feat, const int* __restrict__ ws,
    const uint4* __restrict__ samples, float* __restrict__ out) {
  // pixel = uint4 = 8 channels as 4x half2. [1 front pad][41x164][4 tail pad]
  __shared__ __align__(16) uint4 planeBuf[FRONTPAD + PL_PIX + TAILPAD];

  const int o8 = blockIdx.x;       // channel-octet index (0..31)
  const int b = blockIdx.y;
  const int q = blockIdx.z;
  const int t = threadIdx.x;
  const int row0 = q * QROWS;
  const int c0ch = 8 * o8;

  const int scount = ws[b * 4 + q];
  const int soff = ws[32 + b * 4 + q];
  const uint4* __restrict__ stream = samples + soff;

  // zero front pad, tail pad, and the 4 pad columns of each of 41 rows
  const uint4 zz = {0u, 0u, 0u, 0u};
  if (t < FRONTPAD) planeBuf[t] = zz;
  if (t < TAILPAD) planeBuf[FRONTPAD + PL_PIX + t] = zz;
  if (t < ROWS * 4) {
    const int y = t >> 2;
    planeBuf[FRONTPAD + y * LDSW + FM_W + (t & 3)] = zz;
  }

  // ---- NT-stage rows [row0, row0+41) (clamped) of planes c0ch..c0ch+7
  {
    const f4* __restrict__ sp =
        (const f4*)(feat + ((size_t)b * FM_C + c0ch) * PLANE);
    for (int i = t; i < ROWS * ROW_F4; i += MAIN_BLK) {
      const int y = (int)((unsigned)i / ROW_F4);
      const int j = i - y * ROW_F4;
      const int srow = min(row0 + y, FM_H - 1);  // q=3 top row dup, never read
      const int so = srow * ROW_F4 + j;
      f4 v[8];
#pragma unroll
      for (int c = 0; c < 8; ++c)
        v[c] = __builtin_nontemporal_load(&sp[c * PLANE4 + so]);
      uint4* __restrict__ dst = &planeBuf[FRONTPAD + y * LDSW + 4 * j];
#pragma unroll
      for (int e = 0; e < 4; ++e) {
        const __half2 a0 = __floats2half2_rn(v[0][e], v[1][e]);
        const __half2 a1 = __floats2half2_rn(v[2][e], v[3][e]);
        const __half2 a2 = __floats2half2_rn(v[4][e], v[5][e]);
        const __half2 a3 = __floats2half2_rn(v[6][e], v[7][e]);
        uint4 u;
        u.x = *(const unsigned*)&a0;
        u.y = *(const unsigned*)&a1;
        u.z = *(const unsigned*)&a2;
        u.w = *(const unsigned*)&a3;
        dst[e] = u;
      }
    }
  }
  __syncthreads();

  // ---- gather: one descriptor serves channels c0ch..c0ch+7
  const uint4* __restrict__ pb = planeBuf;
  float* __restrict__ outc = out + (size_t)c0ch * OSP;
#pragma unroll 2
  for (int w = t; w < scount; w += MAIN_BLK) {
    const uint4 sd = stream[w];
    const int bxs = (int)(sd.x & 0x7FFFu);
    const int o10 = bxs + (int)((sd.x >> 15) & 1u) * LDSW;

    const uint4 L0 = pb[bxs];
    const uint4 R0 = pb[bxs + 1];
    const uint4 L1 = pb[o10];
    const uint4 R1 = pb[o10 + 1];

    const __half2 ax = *(const __half2*)&sd.y;
    const __half2 axl = __half2half2(__low2half(ax));
    const __half2 axr = __half2half2(__high2half(ax));

    const __half2 h0a = __hfma2(*(const __half2*)&R0.x, axr,
                                __hmul2(*(const __half2*)&L0.x, axl));
    const __half2 h0b = __hfma2(*(const __half2*)&R0.y, axr,
                                __hmul2(*(const __half2*)&L0.y, axl));
    const __half2 h0c = __hfma2(*(const __half2*)&R0.z, axr,
                                __hmul2(*(const __half2*)&L0.z, axl));
    const __half2 h0d = __hfma2(*(const __half2*)&R0.w, axr,
                                __hmul2(*(const __half2*)&L0.w, axl));
    const __half2 h1a = __hfma2(*(const __half2*)&R1.x, axr,
                                __hmul2(*(const __half2*)&L1.x, axl));
    const __half2 h1b = __hfma2(*(const __half2*)&R1.y, axr,
                                __hmul2(*(const __half2*)&L1.y, axl));
    const __half2 h1c = __hfma2(*(const __half2*)&R1.z, axr,
                                __hmul2(*(const __half2*)&L1.z, axl));
    const __half2 h1d = __hfma2(*(const __half2*)&R1.w, axr,
                                __hmul2(*(const __half2*)&L1.w, axl));

    const float wy1 = (float)((sd.x >> 16) & 0x1FFFu) * (1.0f / 8192.0f);
    const float ay0 = ((sd.x >> 29) & 1u) ? (1.0f - wy1) : 0.0f;
    const float ay1 = ((sd.x >> 30) & 1u) ? wy1 : 0.0f;

    float* __restrict__ dst = outc + sd.z;
    dst[0 * OSP] = ay0 * __low2float(h0a) + ay1 * __low2float(h1a);
    dst[1 * OSP] = ay0 * __high2float(h0a) + ay1 * __high2float(h1a);
    dst[2 * OSP] = ay0 * __low2float(h0b) + ay1 * __low2float(h1b);
    dst[3 * OSP] = ay0 * __high2float(h0b) + ay1 * __high2float(h1b);
    dst[4 * OSP] = ay0 * __low2float(h0c) + ay1 * __low2float(h1c);
    dst[5 * OSP] = ay0 * __high2float(h0c) + ay1 * __high2float(h1c);
    dst[6 * OSP] = ay0 * __low2float(h0d) + ay1 * __low2float(h1d);
    dst[7 * OSP] = ay0 * __high2float(h0d) + ay1 * __high2float(h1d);
  }
}

extern "C" void kernel_launch(void* const* d_in, const int* in_sizes, int n_in,
                              void* d_out, int out_size, void* d_ws, size_t ws_size,
                              hipStream_t stream) {
  const float* feat = (const float*)d_in[0];
  const float* rois = (const float*)d_in[1];
  float* out = (float*)d_out;
  int* ws = (int*)d_ws;
  uint4* samples = (uint4*)((char*)d_ws + WS_SAMPLES_BYTE_OFF);

  const int K = in_sizes[1] / 5;  // 1024
  const int total = K * OSP;

  setup_kernel<<<1, 1024, 0, stream>>>(rois, K, ws);
  precompute_kernel<<<(total + 255) / 256, 256, 0, stream>>>(rois, ws, total,
                                                             samples);
  roi_align_main_kernel<<<dim3(FM_C / 8, FM_N, 4), MAIN_BLK, 0, stream>>>(
      feat, ws, samples, out);
}

// Round 16
// 95.862 us; speedup vs baseline: 1.0189x; 1.0189x over previous
//
#include <hip/hip_runtime.h>
#include <hip/hip_fp16.h>

// RoI Align, ALIGNED=False, SCALE=160.
// feat: (8, 256, 160, 160) fp32; rois: (1024,5); out: (1024, 256, 14, 14) fp32
//
// R16 = R14's 4-channel-per-pixel gather (best measured: 91.35 µs) on
// QUARTER-planes (41 rows x 164 px x 8 B ~= 52.6 KB LDS) so TWO 1024-thread
// blocks co-reside per CU (32 waves, max): block A's serialized staging
// (VMEM) overlaps block B's gather (LDS/VALU/stores) via independent wave
// queues — the overlap every intra-wave scheme (R4-R11) could not produce.
// __launch_bounds__(1024, 8) pins VGPR <= 64 so both blocks fit.
// NT staging loads (R13 isolation: ~22 µs), stride-164 bank pad, ordered
// chunk streams (deterministic: each descriptor carries its own outidx).
//
//  1) setup_kernel (1 block): per-ROI quarter row-counts/starts (q = y0c/40,
//     monotone in oy), per-(b,q) stream sizes + per-k chunk offsets.
//  2) precompute_kernel: uint4 descriptor {bx_local|dyr|wq13|vy0|vy1,
//     ax(half2), outidx, 0} at its in-order chunk slot.
//  3) main: block=(quad, b, q): zero pads; NT-stage 41 rows of 4 planes as
//     half2x2 pixels; gather stream; 4 stores/sample.

#define FM_N 8
#define FM_C 256
#define FM_H 160
#define FM_W 160
#define PLANE (FM_H * FM_W)     // 25600
#define PLANE4 (PLANE / 4)      // 6400
#define OH 14
#define OW 14
#define OSP (OH * OW)           // 196
#define KMAX 1024
#define SCALE_HW 160.0f
#define MAIN_BLK 1024
#define QROWS 40                // quarter height in y0c terms
#define ROWS 41                 // staged rows (1 overlap)
#define LDSW 164                // padded row stride in PIXELS (bank-rotating)
#define ROW_F4 (FM_W / 4)       // 40 f4 chunks per source row
#define PL_PIX (ROWS * LDSW)    // 6724 pixels (uint2 each)
#define FRONTPAD 2              // 2 pixels = 16 B (alignment)
#define TAILPAD 6

typedef float f4 __attribute__((ext_vector_type(4)));

// ws layout (int32 units):
//   [0..32)    cnt32[b*4+q]; [32..64) soff32; [64..64+8*KMAX) kinfo[k]
//   byte 33024: samples[K*196] as uint4
#define WS_KINFO_OFF 64
#define WS_SAMPLES_BYTE_OFF 33024

// Shared between setup & precompute so the quarter test is bit-identical.
__device__ __forceinline__ float iy_of(float y1, float y2, int oy) {
  return fmaf((float)oy * (1.0f / (OH - 1)), y2 - y1, y1) - 0.5f;
}

__device__ __forceinline__ int quarter_of(float y1, float y2, int oy) {
  const int y0 = (int)floorf(iy_of(y1, y2, oy));
  const int y0c = min(max(y0, 0), FM_H - 1);
  return y0c / QROWS;  // 0..3
}

__global__ __launch_bounds__(1024) void setup_kernel(
    const float* __restrict__ rois, int K, int* __restrict__ ws) {
  __shared__ int cnt[32];
  __shared__ int soff[32];
  const int t = threadIdx.x;
  if (t < 32) cnt[t] = 0;
  __syncthreads();
  int n[4] = {0, 0, 0, 0};
  int st[4] = {0, 0, 0, 0};
  int pos[4] = {0, 0, 0, 0};
  int b = 0;
  if (t < K) {
    b = (int)rois[t * 5];
    const float y1 = rois[t * 5 + 2] * SCALE_HW;
    const float y2 = rois[t * 5 + 4] * SCALE_HW;
#pragma unroll
    for (int oy = 0; oy < OH; ++oy) {
      const int q = quarter_of(y1, y2, oy);   // monotone non-decreasing
      if (n[q] == 0) st[q] = oy;
      n[q]++;
    }
#pragma unroll
    for (int q = 0; q < 4; ++q)
      if (n[q]) pos[q] = atomicAdd(&cnt[b * 4 + q], n[q] * OW);
  }
  __syncthreads();
  if (t == 0) {
    int acc = 0;
    for (int i = 0; i < 32; ++i) { soff[i] = acc; acc += cnt[i]; }
  }
  __syncthreads();
  if (t < 32) { ws[t] = cnt[t]; ws[32 + t] = soff[t]; }
  if (t < K) {
#pragma unroll
    for (int q = 0; q < 4; ++q) {
      ws[WS_KINFO_OFF + 8 * t + q] = soff[b * 4 + q] + pos[q];
      ws[WS_KINFO_OFF + 8 * t + 4 + q] = st[q];
    }
  }
}

__global__ __launch_bounds__(256) void precompute_kernel(
    const float* __restrict__ rois, const int* __restrict__ ws, int total,
    uint4* __restrict__ samples) {
  const int g = blockIdx.x * 256 + threadIdx.x;
  if (g >= total) return;
  const int k = g / OSP;
  const int s = g - k * OSP;
  const int oy = s / OW;
  const int ox = s - oy * OW;

  const float x1 = rois[k * 5 + 1] * SCALE_HW;
  const float y1 = rois[k * 5 + 2] * SCALE_HW;
  const float x2 = rois[k * 5 + 3] * SCALE_HW;
  const float y2 = rois[k * 5 + 4] * SCALE_HW;

  // ALIGNED=False index math collapses to ix = fx - 0.5
  const float ix = fmaf((float)ox * (1.0f / (OW - 1)), x2 - x1, x1) - 0.5f;
  const float iy = iy_of(y1, y2, oy);

  const float fx0 = floorf(ix);
  const float fy0 = floorf(iy);
  const int x0 = (int)fx0;
  const int y0 = (int)fy0;
  const float wx1 = ix - fx0;
  const float wy1 = iy - fy0;

  const bool vx0 = (x0 >= 0 && x0 < FM_W);
  const bool vx1 = (x0 + 1 >= 0 && x0 + 1 < FM_W);
  const unsigned vy0 = (y0 >= 0 && y0 < FM_H) ? 1u : 0u;
  const unsigned vy1 = (y0 + 1 >= 0 && y0 + 1 < FM_H) ? 1u : 0u;

  const int x0c = min(max(x0, 0), FM_W - 1);
  const int x1c = min(max(x0 + 1, 0), FM_W - 1);
  const int y0c = min(max(y0, 0), FM_H - 1);
  const int y1c = min(max(y0 + 1, 0), FM_H - 1);

  const int q = y0c / QROWS;        // bit-identical to setup's quarter_of
  const int row0 = q * QROWS;

  // Quarter-local, stride-164 pixel coordinates.
  const int yl0 = y0c - row0;       // 0..40 (y0c=159 in q=3 -> 39; dyr rows ok)
  const int o00 = yl0 * LDSW + x0c;
  const int o01 = yl0 * LDSW + x1c;
  // Left-base: corners always {pix[bx], pix[bx+1]}; border cases carry zero
  // ax weight on the garbage side (pads zeroed in main kernel).
  const int bx = vx1 ? (o01 - 1) : o00;            // [-1, 6719]
  const unsigned bxs = (unsigned)(bx + FRONTPAD);  // 13 bits
  const unsigned dyr = (unsigned)(y1c - y0c);      // 0/1
  unsigned wq = (unsigned)(wy1 * 8192.0f + 0.5f);
  wq = wq > 8191u ? 8191u : wq;

  const __half2 axh = __floats2half2_rn((1.0f - wx1) * (vx0 ? 1.0f : 0.0f),
                                        wx1 * (vx1 ? 1.0f : 0.0f));
  uint4 sd;
  sd.x = bxs | (dyr << 15) | (wq << 16) | (vy0 << 29) | (vy1 << 30);
  sd.y = *(const unsigned*)&axh;
  sd.z = (unsigned)(k * (FM_C * OSP) + s);  // out index (+ c*OSP at store)
  sd.w = 0;

  const int coff = ws[WS_KINFO_OFF + 8 * k + q];
  const int stq = ws[WS_KINFO_OFF + 8 * k + 4 + q];
  samples[coff + (oy - stq) * OW + ox] = sd;
}

__global__ __launch_bounds__(MAIN_BLK, 8) void roi_align_main_kernel(
    const float* __restrict__ feat, const int* __restrict__ ws,
    const uint4* __restrict__ samples, float* __restrict__ out) {
  // pixel = uint2 = 4 channels (2x half2). [2 front pad][41x164][6 tail pad]
  // ~52.6 KB -> TWO blocks per CU (the overlap mechanism).
  __shared__ __align__(16) uint2 planeBuf[FRONTPAD + PL_PIX + TAILPAD];

  const int qd = blockIdx.x;       // channel-quad index (0..63)
  const int b = blockIdx.y;
  const int q = blockIdx.z;        // plane quarter
  const int t = threadIdx.x;
  const int row0 = q * QROWS;
  const int c0ch = 4 * qd;

  const int scount = ws[b * 4 + q];
  const int soff = ws[32 + b * 4 + q];
  const uint4* __restrict__ stream = samples + soff;

  // zero front pad, tail pad, and the 4 pad columns of each of 41 rows
  const uint2 zz = {0u, 0u};
  if (t < FRONTPAD) planeBuf[t] = zz;
  if (t < TAILPAD) planeBuf[FRONTPAD + PL_PIX + t] = zz;
  if (t < ROWS * 4) {
    const int y = t >> 2;
    planeBuf[FRONTPAD + y * LDSW + FM_W + (t & 3)] = zz;
  }

  // ---- NT-stage rows [row0, row0+41) (clamped) of planes c0ch..c0ch+3
  {
    const f4* __restrict__ s0 =
        (const f4*)(feat + ((size_t)b * FM_C + c0ch) * PLANE);
    const f4* __restrict__ s1 = s0 + PLANE4;
    const f4* __restrict__ s2 = s0 + 2 * PLANE4;
    const f4* __restrict__ s3 = s0 + 3 * PLANE4;
    for (int i = t; i < ROWS * ROW_F4; i += MAIN_BLK) {
      const int y = (int)((unsigned)i / ROW_F4);
      const int j = i - y * ROW_F4;
      const int srow = min(row0 + y, FM_H - 1);  // q=3 top row dup, never read
      const int so = srow * ROW_F4 + j;
      const f4 a = __builtin_nontemporal_load(&s0[so]);
      const f4 bb = __builtin_nontemporal_load(&s1[so]);
      const f4 c = __builtin_nontemporal_load(&s2[so]);
      const f4 d = __builtin_nontemporal_load(&s3[so]);
      const __half2 p0l = __floats2half2_rn(a.x, bb.x);
      const __half2 p0h = __floats2half2_rn(c.x, d.x);
      const __half2 p1l = __floats2half2_rn(a.y, bb.y);
      const __half2 p1h = __floats2half2_rn(c.y, d.y);
      const __half2 p2l = __floats2half2_rn(a.z, bb.z);
      const __half2 p2h = __floats2half2_rn(c.z, d.z);
      const __half2 p3l = __floats2half2_rn(a.w, bb.w);
      const __half2 p3h = __floats2half2_rn(c.w, d.w);
      uint4 u01, u23;
      u01.x = *(const unsigned*)&p0l;
      u01.y = *(const unsigned*)&p0h;
      u01.z = *(const unsigned*)&p1l;
      u01.w = *(const unsigned*)&p1h;
      u23.x = *(const unsigned*)&p2l;
      u23.y = *(const unsigned*)&p2h;
      u23.z = *(const unsigned*)&p3l;
      u23.w = *(const unsigned*)&p3h;
      uint4* __restrict__ dst =
          (uint4*)&planeBuf[FRONTPAD + y * LDSW + 4 * j];  // 16B-aligned
      dst[0] = u01;
      dst[1] = u23;
    }
  }
  __syncthreads();

  // ---- gather: one descriptor serves channels c0ch..c0ch+3 (R14 body)
  const uint2* __restrict__ pb = planeBuf;
  float* __restrict__ outc = out + (size_t)c0ch * OSP;
#pragma unroll 2
  for (int w = t; w < scount; w += MAIN_BLK) {
    const uint4 sd = stream[w];
    const int bxs = (int)(sd.x & 0x7FFFu);
    const int o10 = bxs + (int)((sd.x >> 15) & 1u) * LDSW;

    // adjacent pixel pairs -> merged ds_read2_b64 per row
    const uint2 L0 = pb[bxs];
    const uint2 R0 = pb[bxs + 1];
    const uint2 L1 = pb[o10];
    const uint2 R1 = pb[o10 + 1];

    const __half2 ax = *(const __half2*)&sd.y;
    const __half2 axl = __half2half2(__low2half(ax));
    const __half2 axr = __half2half2(__high2half(ax));

    const __half2 hx0l = __hfma2(*(const __half2*)&R0.x, axr,
                                 __hmul2(*(const __half2*)&L0.x, axl));
    const __half2 hx0h = __hfma2(*(const __half2*)&R0.y, axr,
                                 __hmul2(*(const __half2*)&L0.y, axl));
    const __half2 hx1l = __hfma2(*(const __half2*)&R1.x, axr,
                                 __hmul2(*(const __half2*)&L1.x, axl));
    const __half2 hx1h = __hfma2(*(const __half2*)&R1.y, axr,
                                 __hmul2(*(const __half2*)&L1.y, axl));

    const float wy1 = (float)((sd.x >> 16) & 0x1FFFu) * (1.0f / 8192.0f);
    const float ay0 = ((sd.x >> 29) & 1u) ? (1.0f - wy1) : 0.0f;
    const float ay1 = ((sd.x >> 30) & 1u) ? wy1 : 0.0f;

    const float vA = ay0 * __low2float(hx0l) + ay1 * __low2float(hx1l);
    const float vB = ay0 * __high2float(hx0l) + ay1 * __high2float(hx1l);
    const float vC = ay0 * __low2float(hx0h) + ay1 * __low2float(hx1h);
    const float vD = ay0 * __high2float(hx0h) + ay1 * __high2float(hx1h);

    float* __restrict__ dst = outc + sd.z;
    dst[0] = vA;
    dst[OSP] = vB;
    dst[2 * OSP] = vC;
    dst[3 * OSP] = vD;
  }
}

extern "C" void kernel_launch(void* const* d_in, const int* in_sizes, int n_in,
                              void* d_out, int out_size, void* d_ws, size_t ws_size,
                              hipStream_t stream) {
  const float* feat = (const float*)d_in[0];
  const float* rois = (const float*)d_in[1];
  float* out = (float*)d_out;
  int* ws = (int*)d_ws;
  uint4* samples = (uint4*)((char*)d_ws + WS_SAMPLES_BYTE_OFF);

  const int K = in_sizes[1] / 5;  // 1024
  const int total = K * OSP;

  setup_kernel<<<1, 1024, 0, stream>>>(rois, K, ws);
  precompute_kernel<<<(total + 255) / 256, 256, 0, stream>>>(rois, ws, total,
                                                             samples);
  roi_align_main_kernel<<<dim3(FM_C / 4, FM_N, 4), MAIN_BLK, 0, stream>>>(
      feat, ws, samples, out);
}

// Round 17
// 91.999 us; speedup vs baseline: 1.0617x; 1.0420x over previous
//
#include <hip/hip_runtime.h>
#include <hip/hip_fp16.h>

// RoI Align, ALIGNED=False, SCALE=160.
// feat: (8, 256, 160, 160) fp32; rois: (1024,5); out: (1024, 256, 14, 14) fp32
//
// R17 = R14 champion (91.35 µs) + gather unroll 4 (desc-load MLP: 16 waves/CU
// only partially hide ~250 cy L2 latency at unroll 2).
// Structure (all isolation-proven): half-plane split via iy-monotonicity,
// 4 channels per LDS pixel (half2x2, 8 B/px, 81x164 rows ~= 104 KB), NT
// staging loads (~22 µs, R13), stride-164 bank pad (7.6M -> 4.8M conflict
// cycles, R12), ordered chunk streams -> coalesced stores (R8 lesson),
// per-sample outidx -> deterministic output. Overlap schemes all refuted
// (R4-R11, R16): vmcnt FIFO + lockstep co-residency.

#define FM_N 8
#define FM_C 256
#define FM_H 160
#define FM_W 160
#define PLANE (FM_H * FM_W)     // 25600
#define PLANE4 (PLANE / 4)      // 6400
#define OH 14
#define OW 14
#define OSP (OH * OW)           // 196
#define KMAX 1024
#define SCALE_HW 160.0f
#define MAIN_BLK 1024
#define ROWS 81                 // half-plane rows (1 overlap row)
#define LDSW 164                // padded row stride in PIXELS (164%32=4)
#define ROW_F4 (FM_W / 4)       // 40 f4 chunks per source row
#define PL_PIX (ROWS * LDSW)    // 13284 pixels
#define PL_F4 (ROWS * ROW_F4)   // 3240 f4 chunks per plane half
#define FRONTPAD 2              // pixels (16 B, keeps rows 16B-aligned)
#define TAILPAD 6

typedef float f4 __attribute__((ext_vector_type(4)));

// ws layout (int32 units):
//   [0..16)   cnt16[b*2+h]; [16..32) soff16; [32..32+3*KMAX) kinfo[k]
//   byte 12544: samples[K*196] as uint4
#define WS_KINFO_OFF 32
#define WS_SAMPLES_BYTE_OFF 12544

// Shared between setup & precompute so the half-split test is bit-identical.
__device__ __forceinline__ float iy_of(float y1, float y2, int oy) {
  return fmaf((float)oy * (1.0f / (OH - 1)), y2 - y1, y1) - 0.5f;
}

__global__ __launch_bounds__(1024) void setup_kernel(
    const float* __restrict__ rois, int K, int* __restrict__ ws) {
  __shared__ int cnt[16];
  __shared__ int soff[16];
  const int t = threadIdx.x;
  if (t < 16) cnt[t] = 0;
  __syncthreads();
  int posA = 0, posB = 0, c0 = 0, b = 0;
  if (t < K) {
    b = (int)rois[t * 5];
    const float y1 = rois[t * 5 + 2] * SCALE_HW;
    const float y2 = rois[t * 5 + 4] * SCALE_HW;
#pragma unroll
    for (int oy = 0; oy < OH; ++oy)
      c0 += (iy_of(y1, y2, oy) < 80.0f) ? 1 : 0;   // monotonic in oy
    posA = atomicAdd(&cnt[b * 2 + 0], c0 * OW);
    posB = atomicAdd(&cnt[b * 2 + 1], (OH - c0) * OW);
  }
  __syncthreads();
  if (t == 0) {
    int acc = 0;
    for (int i = 0; i < 16; ++i) { soff[i] = acc; acc += cnt[i]; }
  }
  __syncthreads();
  if (t < 16) { ws[t] = cnt[t]; ws[16 + t] = soff[t]; }
  if (t < K) {
    ws[WS_KINFO_OFF + 3 * t + 0] = soff[b * 2 + 0] + posA;
    ws[WS_KINFO_OFF + 3 * t + 1] = soff[b * 2 + 1] + posB;
    ws[WS_KINFO_OFF + 3 * t + 2] = c0;
  }
}

__global__ __launch_bounds__(256) void precompute_kernel(
    const float* __restrict__ rois, const int* __restrict__ ws, int total,
    uint4* __restrict__ samples) {
  const int g = blockIdx.x * 256 + threadIdx.x;
  if (g >= total) return;
  const int k = g / OSP;
  const int s = g - k * OSP;
  const int oy = s / OW;
  const int ox = s - oy * OW;

  const float x1 = rois[k * 5 + 1] * SCALE_HW;
  const float y1 = rois[k * 5 + 2] * SCALE_HW;
  const float x2 = rois[k * 5 + 3] * SCALE_HW;
  const float y2 = rois[k * 5 + 4] * SCALE_HW;

  // ALIGNED=False index math collapses to ix = fx - 0.5
  const float ix = fmaf((float)ox * (1.0f / (OW - 1)), x2 - x1, x1) - 0.5f;
  const float iy = iy_of(y1, y2, oy);

  const float fx0 = floorf(ix);
  const float fy0 = floorf(iy);
  const int x0 = (int)fx0;
  const int y0 = (int)fy0;
  const float wx1 = ix - fx0;
  const float wy1 = iy - fy0;

  const bool vx0 = (x0 >= 0 && x0 < FM_W);
  const bool vx1 = (x0 + 1 >= 0 && x0 + 1 < FM_W);
  const unsigned vy0 = (y0 >= 0 && y0 < FM_H) ? 1u : 0u;
  const unsigned vy1 = (y0 + 1 >= 0 && y0 + 1 < FM_H) ? 1u : 0u;

  const int x0c = min(max(x0, 0), FM_W - 1);
  const int x1c = min(max(x0 + 1, 0), FM_W - 1);
  const int y0c = min(max(y0, 0), FM_H - 1);
  const int y1c = min(max(y0 + 1, 0), FM_H - 1);

  const int ca = ws[WS_KINFO_OFF + 3 * k + 0];
  const int cb = ws[WS_KINFO_OFF + 3 * k + 1];
  const int c0 = ws[WS_KINFO_OFF + 3 * k + 2];
  const int h = (oy >= c0) ? 1 : 0;   // == (iy >= 80) by monotonicity
  const int row0 = h ? 79 : 0;

  // Half-plane-local, stride-164 pixel coordinates.
  const int yl0 = y0c - row0;
  const int o00 = yl0 * LDSW + x0c;
  const int o01 = yl0 * LDSW + x1c;
  // Left-base: corners always {pix[bx], pix[bx+1]}; border cases carry zero
  // ax weight on the garbage side (pads zeroed in main kernel).
  const int bx = vx1 ? (o01 - 1) : o00;            // [-1, 13279]
  const unsigned bxs = (unsigned)(bx + FRONTPAD);  // 15 bits
  const unsigned dyr = (unsigned)(y1c - y0c);      // 0/1
  unsigned wq = (unsigned)(wy1 * 8192.0f + 0.5f);
  wq = wq > 8191u ? 8191u : wq;

  const __half2 axh = __floats2half2_rn((1.0f - wx1) * (vx0 ? 1.0f : 0.0f),
                                        wx1 * (vx1 ? 1.0f : 0.0f));
  uint4 sd;
  sd.x = bxs | (dyr << 15) | (wq << 16) | (vy0 << 29) | (vy1 << 30);
  sd.y = *(const unsigned*)&axh;
  sd.z = (unsigned)(k * (FM_C * OSP) + s);  // out index (+ c*OSP at store)
  sd.w = 0;

  const int pos = h ? (cb + (oy - c0) * OW + ox) : (ca + oy * OW + ox);
  samples[pos] = sd;
}

__global__ __launch_bounds__(MAIN_BLK) void roi_align_main_kernel(
    const float* __restrict__ feat, const int* __restrict__ ws,
    const uint4* __restrict__ samples, float* __restrict__ out) {
  // pixel = uint2 = 4 channels as 2x half2. [2 front pad][81x164][6 tail pad]
  __shared__ __align__(16) uint2 planeBuf[FRONTPAD + PL_PIX + TAILPAD];

  const int q = blockIdx.x;        // channel-quad index (0..63)
  const int b = blockIdx.y;
  const int h = blockIdx.z;
  const int t = threadIdx.x;
  const int row0 = h ? 79 : 0;
  const int c0ch = 4 * q;

  const int scount = ws[b * 2 + h];
  const int soff = ws[16 + b * 2 + h];
  const uint4* __restrict__ stream = samples + soff;

  // zero front pad, tail pad, and the 4 pad columns of each of 81 rows
  const uint2 zz = {0u, 0u};
  if (t < FRONTPAD) planeBuf[t] = zz;
  if (t < TAILPAD) planeBuf[FRONTPAD + PL_PIX + t] = zz;
  if (t < ROWS * 4) {
    const int y = t >> 2;
    planeBuf[FRONTPAD + y * LDSW + FM_W + (t & 3)] = zz;
  }

  // ---- NT-stage rows [row0, row0+81) of planes c0ch..c0ch+3 as half2x2
  {
    const f4* __restrict__ s0 =
        (const f4*)(feat + ((size_t)b * FM_C + c0ch) * PLANE) + row0 * ROW_F4;
    const f4* __restrict__ s1 = s0 + PLANE4;
    const f4* __restrict__ s2 = s0 + 2 * PLANE4;
    const f4* __restrict__ s3 = s0 + 3 * PLANE4;
    for (int i = t; i < PL_F4; i += MAIN_BLK) {
      const f4 a = __builtin_nontemporal_load(&s0[i]);
      const f4 bb = __builtin_nontemporal_load(&s1[i]);
      const f4 c = __builtin_nontemporal_load(&s2[i]);
      const f4 d = __builtin_nontemporal_load(&s3[i]);
      const int y = (int)((unsigned)i / ROW_F4);
      const int j = i - y * ROW_F4;
      const __half2 p0l = __floats2half2_rn(a.x, bb.x);
      const __half2 p0h = __floats2half2_rn(c.x, d.x);
      const __half2 p1l = __floats2half2_rn(a.y, bb.y);
      const __half2 p1h = __floats2half2_rn(c.y, d.y);
      const __half2 p2l = __floats2half2_rn(a.z, bb.z);
      const __half2 p2h = __floats2half2_rn(c.z, d.z);
      const __half2 p3l = __floats2half2_rn(a.w, bb.w);
      const __half2 p3h = __floats2half2_rn(c.w, d.w);
      uint4 u01, u23;
      u01.x = *(const unsigned*)&p0l;
      u01.y = *(const unsigned*)&p0h;
      u01.z = *(const unsigned*)&p1l;
      u01.w = *(const unsigned*)&p1h;
      u23.x = *(const unsigned*)&p2l;
      u23.y = *(const unsigned*)&p2h;
      u23.z = *(const unsigned*)&p3l;
      u23.w = *(const unsigned*)&p3h;
      uint4* __restrict__ dst =
          (uint4*)&planeBuf[FRONTPAD + y * LDSW + 4 * j];  // 16B-aligned
      dst[0] = u01;
      dst[1] = u23;
    }
  }
  __syncthreads();

  // ---- gather: one descriptor serves channels c0ch..c0ch+3; unroll 4 for
  // desc-load MLP (4 in flight/wave vs 2).
  const uint2* __restrict__ pb = planeBuf;
  float* __restrict__ outc = out + (size_t)c0ch * OSP;
#pragma unroll 4
  for (int w = t; w < scount; w += MAIN_BLK) {
    const uint4 sd = stream[w];
    const int bxs = (int)(sd.x & 0x7FFFu);
    const int o10 = bxs + (int)((sd.x >> 15) & 1u) * LDSW;

    // adjacent pixel pairs -> merged ds_read2_b64 per row
    const uint2 L0 = pb[bxs];
    const uint2 R0 = pb[bxs + 1];
    const uint2 L1 = pb[o10];
    const uint2 R1 = pb[o10 + 1];

    const __half2 ax = *(const __half2*)&sd.y;
    const __half2 axl = __half2half2(__low2half(ax));
    const __half2 axr = __half2half2(__high2half(ax));

    const __half2 hx0l = __hfma2(*(const __half2*)&R0.x, axr,
                                 __hmul2(*(const __half2*)&L0.x, axl));
    const __half2 hx0h = __hfma2(*(const __half2*)&R0.y, axr,
                                 __hmul2(*(const __half2*)&L0.y, axl));
    const __half2 hx1l = __hfma2(*(const __half2*)&R1.x, axr,
                                 __hmul2(*(const __half2*)&L1.x, axl));
    const __half2 hx1h = __hfma2(*(const __half2*)&R1.y, axr,
                                 __hmul2(*(const __half2*)&L1.y, axl));

    const float wy1 = (float)((sd.x >> 16) & 0x1FFFu) * (1.0f / 8192.0f);
    const float ay0 = ((sd.x >> 29) & 1u) ? (1.0f - wy1) : 0.0f;
    const float ay1 = ((sd.x >> 30) & 1u) ? wy1 : 0.0f;

    const float vA = ay0 * __low2float(hx0l) + ay1 * __low2float(hx1l);
    const float vB = ay0 * __high2float(hx0l) + ay1 * __high2float(hx1l);
    const float vC = ay0 * __low2float(hx0h) + ay1 * __low2float(hx1h);
    const float vD = ay0 * __high2float(hx0h) + ay1 * __high2float(hx1h);

    float* __restrict__ dst = outc + sd.z;
    dst[0] = vA;
    dst[OSP] = vB;
    dst[2 * OSP] = vC;
    dst[3 * OSP] = vD;
  }
}

extern "C" void kernel_launch(void* const* d_in, const int* in_sizes, int n_in,
                              void* d_out, int out_size, void* d_ws, size_t ws_size,
                              hipStream_t stream) {
  const float* feat = (const float*)d_in[0];
  const float* rois = (const float*)d_in[1];
  float* out = (float*)d_out;
  int* ws = (int*)d_ws;
  uint4* samples = (uint4*)((char*)d_ws + WS_SAMPLES_BYTE_OFF);

  const int K = in_sizes[1] / 5;  // 1024
  const int total = K * OSP;

  setup_kernel<<<1, 1024, 0, stream>>>(rois, K, ws);
  precompute_kernel<<<(total + 255) / 256, 256, 0, stream>>>(rois, ws, total,
                                                             samples);
  roi_align_main_kernel<<<dim3(FM_C / 4, FM_N, 2), MAIN_BLK, 0, stream>>>(
      feat, ws, samples, out);
}

// Round 18
// 91.130 us; speedup vs baseline: 1.0718x; 1.0095x over previous
//
#include <hip/hip_runtime.h>
#include <hip/hip_fp16.h>

// RoI Align, ALIGNED=False, SCALE=160.
// feat: (8, 256, 160, 160) fp32; rois: (1024,5); out: (1024, 256, 14, 14) fp32
//
// FINAL = R14 champion (91.35 µs), byte-for-byte (R17's unroll-4 was neutral;
// reverted to the measured-best unroll 2).
// Structure (each element isolation-proven):
//  - half-plane split via iy-monotonicity (rows [0,c0)->half0, [c0,14)->half1)
//  - 4 channels per LDS pixel (half2x2, 8 B/px, 81x164 rows ~= 104 KB): one
//    16 B descriptor + 2 merged ds_read2_b64 + one weight-decode serve 4 chans
//  - NT staging loads (keeps 210 MB stream out of L2; worth ~22 µs, R12/R13)
//  - stride-164 row pad (bank-rotating; conflicts 7.6M -> 4.8M cyc, R12)
//  - ordered chunk streams -> coalesced stores (R8 lesson); per-sample outidx
//    -> deterministic output regardless of atomic chunk-placement order
// Overlap schemes all refuted on this workload (R4-R11, R16): intra-wave
// prefetch dies on the vmcnt FIFO; co-resident blocks run in lockstep.

#define FM_N 8
#define FM_C 256
#define FM_H 160
#define FM_W 160
#define PLANE (FM_H * FM_W)     // 25600
#define PLANE4 (PLANE / 4)      // 6400
#define OH 14
#define OW 14
#define OSP (OH * OW)           // 196
#define KMAX 1024
#define SCALE_HW 160.0f
#define MAIN_BLK 1024
#define ROWS 81                 // half-plane rows (1 overlap row)
#define LDSW 164                // padded row stride in PIXELS (164%32=4)
#define ROW_F4 (FM_W / 4)       // 40 f4 chunks per source row
#define PL_PIX (ROWS * LDSW)    // 13284 pixels
#define PL_F4 (ROWS * ROW_F4)   // 3240 f4 chunks per plane half
#define FRONTPAD 2              // pixels (16 B, keeps rows 16B-aligned)
#define TAILPAD 6

typedef float f4 __attribute__((ext_vector_type(4)));

// ws layout (int32 units):
//   [0..16)   cnt16[b*2+h]; [16..32) soff16; [32..32+3*KMAX) kinfo[k]
//   byte 12544: samples[K*196] as uint4
#define WS_KINFO_OFF 32
#define WS_SAMPLES_BYTE_OFF 12544

// Shared between setup & precompute so the half-split test is bit-identical.
__device__ __forceinline__ float iy_of(float y1, float y2, int oy) {
  return fmaf((float)oy * (1.0f / (OH - 1)), y2 - y1, y1) - 0.5f;
}

__global__ __launch_bounds__(1024) void setup_kernel(
    const float* __restrict__ rois, int K, int* __restrict__ ws) {
  __shared__ int cnt[16];
  __shared__ int soff[16];
  const int t = threadIdx.x;
  if (t < 16) cnt[t] = 0;
  __syncthreads();
  int posA = 0, posB = 0, c0 = 0, b = 0;
  if (t < K) {
    b = (int)rois[t * 5];
    const float y1 = rois[t * 5 + 2] * SCALE_HW;
    const float y2 = rois[t * 5 + 4] * SCALE_HW;
#pragma unroll
    for (int oy = 0; oy < OH; ++oy)
      c0 += (iy_of(y1, y2, oy) < 80.0f) ? 1 : 0;   // monotonic in oy
    posA = atomicAdd(&cnt[b * 2 + 0], c0 * OW);
    posB = atomicAdd(&cnt[b * 2 + 1], (OH - c0) * OW);
  }
  __syncthreads();
  if (t == 0) {
    int acc = 0;
    for (int i = 0; i < 16; ++i) { soff[i] = acc; acc += cnt[i]; }
  }
  __syncthreads();
  if (t < 16) { ws[t] = cnt[t]; ws[16 + t] = soff[t]; }
  if (t < K) {
    ws[WS_KINFO_OFF + 3 * t + 0] = soff[b * 2 + 0] + posA;
    ws[WS_KINFO_OFF + 3 * t + 1] = soff[b * 2 + 1] + posB;
    ws[WS_KINFO_OFF + 3 * t + 2] = c0;
  }
}

__global__ __launch_bounds__(256) void precompute_kernel(
    const float* __restrict__ rois, const int* __restrict__ ws, int total,
    uint4* __restrict__ samples) {
  const int g = blockIdx.x * 256 + threadIdx.x;
  if (g >= total) return;
  const int k = g / OSP;
  const int s = g - k * OSP;
  const int oy = s / OW;
  const int ox = s - oy * OW;

  const float x1 = rois[k * 5 + 1] * SCALE_HW;
  const float y1 = rois[k * 5 + 2] * SCALE_HW;
  const float x2 = rois[k * 5 + 3] * SCALE_HW;
  const float y2 = rois[k * 5 + 4] * SCALE_HW;

  // ALIGNED=False index math collapses to ix = fx - 0.5
  const float ix = fmaf((float)ox * (1.0f / (OW - 1)), x2 - x1, x1) - 0.5f;
  const float iy = iy_of(y1, y2, oy);

  const float fx0 = floorf(ix);
  const float fy0 = floorf(iy);
  const int x0 = (int)fx0;
  const int y0 = (int)fy0;
  const float wx1 = ix - fx0;
  const float wy1 = iy - fy0;

  const bool vx0 = (x0 >= 0 && x0 < FM_W);
  const bool vx1 = (x0 + 1 >= 0 && x0 + 1 < FM_W);
  const unsigned vy0 = (y0 >= 0 && y0 < FM_H) ? 1u : 0u;
  const unsigned vy1 = (y0 + 1 >= 0 && y0 + 1 < FM_H) ? 1u : 0u;

  const int x0c = min(max(x0, 0), FM_W - 1);
  const int x1c = min(max(x0 + 1, 0), FM_W - 1);
  const int y0c = min(max(y0, 0), FM_H - 1);
  const int y1c = min(max(y0 + 1, 0), FM_H - 1);

  const int ca = ws[WS_KINFO_OFF + 3 * k + 0];
  const int cb = ws[WS_KINFO_OFF + 3 * k + 1];
  const int c0 = ws[WS_KINFO_OFF + 3 * k + 2];
  const int h = (oy >= c0) ? 1 : 0;   // == (iy >= 80) by monotonicity
  const int row0 = h ? 79 : 0;

  // Half-plane-local, stride-164 pixel coordinates.
  const int yl0 = y0c - row0;
  const int o00 = yl0 * LDSW + x0c;
  const int o01 = yl0 * LDSW + x1c;
  // Left-base: corners always {pix[bx], pix[bx+1]}; border cases carry zero
  // ax weight on the garbage side (pads zeroed in main kernel).
  const int bx = vx1 ? (o01 - 1) : o00;            // [-1, 13279]
  const unsigned bxs = (unsigned)(bx + FRONTPAD);  // 15 bits
  const unsigned dyr = (unsigned)(y1c - y0c);      // 0/1
  unsigned wq = (unsigned)(wy1 * 8192.0f + 0.5f);
  wq = wq > 8191u ? 8191u : wq;

  const __half2 axh = __floats2half2_rn((1.0f - wx1) * (vx0 ? 1.0f : 0.0f),
                                        wx1 * (vx1 ? 1.0f : 0.0f));
  uint4 sd;
  sd.x = bxs | (dyr << 15) | (wq << 16) | (vy0 << 29) | (vy1 << 30);
  sd.y = *(const unsigned*)&axh;
  sd.z = (unsigned)(k * (FM_C * OSP) + s);  // out index (+ c*OSP at store)
  sd.w = 0;

  const int pos = h ? (cb + (oy - c0) * OW + ox) : (ca + oy * OW + ox);
  samples[pos] = sd;
}

__global__ __launch_bounds__(MAIN_BLK) void roi_align_main_kernel(
    const float* __restrict__ feat, const int* __restrict__ ws,
    const uint4* __restrict__ samples, float* __restrict__ out) {
  // pixel = uint2 = 4 channels as 2x half2. [2 front pad][81x164][6 tail pad]
  __shared__ __align__(16) uint2 planeBuf[FRONTPAD + PL_PIX + TAILPAD];

  const int q = blockIdx.x;        // channel-quad index (0..63)
  const int b = blockIdx.y;
  const int h = blockIdx.z;
  const int t = threadIdx.x;
  const int row0 = h ? 79 : 0;
  const int c0ch = 4 * q;

  const int scount = ws[b * 2 + h];
  const int soff = ws[16 + b * 2 + h];
  const uint4* __restrict__ stream = samples + soff;

  // zero front pad, tail pad, and the 4 pad columns of each of 81 rows
  const uint2 zz = {0u, 0u};
  if (t < FRONTPAD) planeBuf[t] = zz;
  if (t < TAILPAD) planeBuf[FRONTPAD + PL_PIX + t] = zz;
  if (t < ROWS * 4) {
    const int y = t >> 2;
    planeBuf[FRONTPAD + y * LDSW + FM_W + (t & 3)] = zz;
  }

  // ---- NT-stage rows [row0, row0+81) of planes c0ch..c0ch+3 as half2x2
  {
    const f4* __restrict__ s0 =
        (const f4*)(feat + ((size_t)b * FM_C + c0ch) * PLANE) + row0 * ROW_F4;
    const f4* __restrict__ s1 = s0 + PLANE4;
    const f4* __restrict__ s2 = s0 + 2 * PLANE4;
    const f4* __restrict__ s3 = s0 + 3 * PLANE4;
    for (int i = t; i < PL_F4; i += MAIN_BLK) {
      const f4 a = __builtin_nontemporal_load(&s0[i]);
      const f4 bb = __builtin_nontemporal_load(&s1[i]);
      const f4 c = __builtin_nontemporal_load(&s2[i]);
      const f4 d = __builtin_nontemporal_load(&s3[i]);
      const int y = (int)((unsigned)i / ROW_F4);
      const int j = i - y * ROW_F4;
      const __half2 p0l = __floats2half2_rn(a.x, bb.x);
      const __half2 p0h = __floats2half2_rn(c.x, d.x);
      const __half2 p1l = __floats2half2_rn(a.y, bb.y);
      const __half2 p1h = __floats2half2_rn(c.y, d.y);
      const __half2 p2l = __floats2half2_rn(a.z, bb.z);
      const __half2 p2h = __floats2half2_rn(c.z, d.z);
      const __half2 p3l = __floats2half2_rn(a.w, bb.w);
      const __half2 p3h = __floats2half2_rn(c.w, d.w);
      uint4 u01, u23;
      u01.x = *(const unsigned*)&p0l;
      u01.y = *(const unsigned*)&p0h;
      u01.z = *(const unsigned*)&p1l;
      u01.w = *(const unsigned*)&p1h;
      u23.x = *(const unsigned*)&p2l;
      u23.y = *(const unsigned*)&p2h;
      u23.z = *(const unsigned*)&p3l;
      u23.w = *(const unsigned*)&p3h;
      uint4* __restrict__ dst =
          (uint4*)&planeBuf[FRONTPAD + y * LDSW + 4 * j];  // 16B-aligned
      dst[0] = u01;
      dst[1] = u23;
    }
  }
  __syncthreads();

  // ---- gather: one descriptor serves channels c0ch..c0ch+3 (unroll 2 =
  // measured-best; unroll 4 was neutral in R17)
  const uint2* __restrict__ pb = planeBuf;
  float* __restrict__ outc = out + (size_t)c0ch * OSP;
#pragma unroll 2
  for (int w = t; w < scount; w += MAIN_BLK) {
    const uint4 sd = stream[w];
    const int bxs = (int)(sd.x & 0x7FFFu);
    const int o10 = bxs + (int)((sd.x >> 15) & 1u) * LDSW;

    // adjacent pixel pairs -> merged ds_read2_b64 per row
    const uint2 L0 = pb[bxs];
    const uint2 R0 = pb[bxs + 1];
    const uint2 L1 = pb[o10];
    const uint2 R1 = pb[o10 + 1];

    const __half2 ax = *(const __half2*)&sd.y;
    const __half2 axl = __half2half2(__low2half(ax));
    const __half2 axr = __half2half2(__high2half(ax));

    const __half2 hx0l = __hfma2(*(const __half2*)&R0.x, axr,
                                 __hmul2(*(const __half2*)&L0.x, axl));
    const __half2 hx0h = __hfma2(*(const __half2*)&R0.y, axr,
                                 __hmul2(*(const __half2*)&L0.y, axl));
    const __half2 hx1l = __hfma2(*(const __half2*)&R1.x, axr,
                                 __hmul2(*(const __half2*)&L1.x, axl));
    const __half2 hx1h = __hfma2(*(const __half2*)&R1.y, axr,
                                 __hmul2(*(const __half2*)&L1.y, axl));

    const float wy1 = (float)((sd.x >> 16) & 0x1FFFu) * (1.0f / 8192.0f);
    const float ay0 = ((sd.x >> 29) & 1u) ? (1.0f - wy1) : 0.0f;
    const float ay1 = ((sd.x >> 30) & 1u) ? wy1 : 0.0f;

    const float vA = ay0 * __low2float(hx0l) + ay1 * __low2float(hx1l);
    const float vB = ay0 * __high2float(hx0l) + ay1 * __high2float(hx1l);
    const float vC = ay0 * __low2float(hx0h) + ay1 * __low2float(hx1h);
    const float vD = ay0 * __high2float(hx0h) + ay1 * __high2float(hx1h);

    float* __restrict__ dst = outc + sd.z;
    dst[0] = vA;
    dst[OSP] = vB;
    dst[2 * OSP] = vC;
    dst[3 * OSP] = vD;
  }
}

extern "C" void kernel_launch(void* const* d_in, const int* in_sizes, int n_in,
                              void* d_out, int out_size, void* d_ws, size_t ws_size,
                              hipStream_t stream) {
  const float* feat = (const float*)d_in[0];
  const float* rois = (const float*)d_in[1];
  float* out = (float*)d_out;
  int* ws = (int*)d_ws;
  uint4* samples = (uint4*)((char*)d_ws + WS_SAMPLES_BYTE_OFF);

  const int K = in_sizes[1] / 5;  // 1024
  const int total = K * OSP;

  setup_kernel<<<1, 1024, 0, stream>>>(rois, K, ws);
  precompute_kernel<<<(total + 255) / 256, 256, 0, stream>>>(rois, ws, total,
                                                             samples);
  roi_align_main_kernel<<<dim3(FM_C / 4, FM_N, 2), MAIN_BLK, 0, stream>>>(
      feat, ws, samples, out);
}